// Round 1
// baseline (1331.391 us; speedup 1.0000x reference)
//
#include <hip/hip_runtime.h>
#include <math.h>

// Problem constants (fixed by the reference)
#define B_   8
#define S_   2048
#define H_   16
#define D_   64
#define DM_  1024
#define W_   4
#define SC_  512   // (S - W)/W + 1

// ---------------------------------------------------------------------------
// Kernel 1: strided conv compression  kc/vc[b,h,t,dout] =
//   bias[dout] + sum_{w,din} x[b, t*4+w, h, din] * kern[w,din,dout]
// Block: 256 thr, handles 32 t-values of one (b,h). Grid = B*H*(SC/32) = 2048.
// ---------------------------------------------------------------------------
__global__ __launch_bounds__(256) void compress_kernel(
    const float* __restrict__ x,     // [B,S,H,D]
    const float* __restrict__ kern,  // [W*D, D] = [256,64]
    const float* __restrict__ bias,  // [64]
    float* __restrict__ y)           // [B,H,SC,D]
{
    __shared__ float xs[128 * 64];   // 32 t * 4 w rows of 64 -> 32 KB
    const int tid   = threadIdx.x;
    const int bid   = blockIdx.x;
    const int chunk = bid & 15;      // 16 chunks of 32 t per (b,h)
    const int bh    = bid >> 4;
    const int h     = bh & 15;
    const int b     = bh >> 4;
    const int s0    = chunk * 128;   // first input row

    // stage 128 rows x 64 floats (coalesced in 16-lane groups)
    float4* xs4 = (float4*)xs;
    #pragma unroll
    for (int r = 0; r < 8; ++r) {
        int idx = r * 256 + tid;            // 0..2047 float4s
        int row = idx >> 4, c4 = idx & 15;
        const float4* p = (const float4*)(x + (((size_t)(b * S_ + s0 + row) * H_ + h) * D_)) + c4;
        xs4[row * 16 + c4] = *p;
    }
    __syncthreads();

    const int dout = tid & 63;
    const int g    = tid >> 6;       // wave id; wave g handles t_local g*8..g*8+7
    float bv = bias[dout];
    float acc[8];
    #pragma unroll
    for (int tl = 0; tl < 8; ++tl) acc[tl] = bv;

    const float4* xt4 = xs4 + g * 512;   // (g*8)*256 floats / 4

    #pragma unroll 2
    for (int i4 = 0; i4 < 64; ++i4) {    // i = w*64+din, vectorized by 4
        float4 xv[8];
        #pragma unroll
        for (int tl = 0; tl < 8; ++tl) xv[tl] = xt4[tl * 64 + i4];
        #pragma unroll
        for (int q = 0; q < 4; ++q) {
            float kw = kern[(i4 * 4 + q) * 64 + dout];   // coalesced, L2-hot
            #pragma unroll
            for (int tl = 0; tl < 8; ++tl)
                acc[tl] += ((const float*)&xv[tl])[q] * kw;
        }
    }

    const int t0 = chunk * 32;
    #pragma unroll
    for (int tl = 0; tl < 8; ++tl) {
        int t = t0 + g * 8 + tl;
        y[((size_t)bh * SC_ + t) * D_ + dout] = acc[tl];
    }
}

// ---------------------------------------------------------------------------
// Kernel 2: fused attention (flash-style). One thread = one q-row.
// Block 256 thr = 256 rows of one (b,h). Grid = B*H*(S/256) = 1024.
// K/V staged in LDS 64 rows at a time; online softmax in 16-score subtiles.
// ---------------------------------------------------------------------------
__global__ __launch_bounds__(256) void attn_kernel(
    const float* __restrict__ q,    // [B,S,H,D]
    const float* __restrict__ kc,   // [B,H,SC,D]
    const float* __restrict__ vc,   // [B,H,SC,D]
    float* __restrict__ xout)       // [B,S,DM]
{
    __shared__ float4 lk[64 * 16];  // 16 KB
    __shared__ float4 lv[64 * 16];  // 16 KB
    const int tid    = threadIdx.x;
    const int bid    = blockIdx.x;
    const int schunk = bid & 7;
    const int bh     = bid >> 3;
    const int h      = bh & 15;
    const int b      = bh >> 4;
    const int s      = schunk * 256 + tid;

    float qr[64];
    {
        const float4* qp = (const float4*)(q + (((size_t)(b * S_ + s) * H_ + h) * D_));
        #pragma unroll
        for (int d4 = 0; d4 < 16; ++d4) {
            float4 v = qp[d4];
            qr[d4*4+0] = v.x; qr[d4*4+1] = v.y; qr[d4*4+2] = v.z; qr[d4*4+3] = v.w;
        }
    }
    float o[64];
    #pragma unroll
    for (int d = 0; d < 64; ++d) o[d] = 0.f;
    float m = -1e30f, l = 0.f;

    const float4* kt = (const float4*)(kc + (size_t)bh * SC_ * D_);
    const float4* vt = (const float4*)(vc + (size_t)bh * SC_ * D_);

    for (int tile = 0; tile < SC_ / 64; ++tile) {
        __syncthreads();
        #pragma unroll
        for (int r = 0; r < 4; ++r) {     // 1024 float4 per buffer, 4/thread
            int idx = r * 256 + tid;
            lk[idx] = kt[tile * 1024 + idx];
            lv[idx] = vt[tile * 1024 + idx];
        }
        __syncthreads();

        for (int sub = 0; sub < 4; ++sub) {
            float sc[16];
            #pragma unroll
            for (int j = 0; j < 16; ++j) {
                const float4* kr = &lk[(sub * 16 + j) * 16];
                float ax = 0.f, ay = 0.f, az = 0.f, aw = 0.f;
                #pragma unroll
                for (int d4 = 0; d4 < 16; ++d4) {
                    float4 kv = kr[d4];
                    ax += qr[d4*4+0] * kv.x;
                    ay += qr[d4*4+1] * kv.y;
                    az += qr[d4*4+2] * kv.z;
                    aw += qr[d4*4+3] * kv.w;
                }
                sc[j] = (ax + ay + az + aw) * 0.125f;
            }
            float tm = sc[0];
            #pragma unroll
            for (int j = 1; j < 16; ++j) tm = fmaxf(tm, sc[j]);
            float mn = fmaxf(m, tm);
            float f = __expf(m - mn);     // m = -1e30 first pass -> f = 0
            l *= f;
            #pragma unroll
            for (int d = 0; d < 64; ++d) o[d] *= f;
            #pragma unroll
            for (int j = 0; j < 16; ++j) {
                float p = __expf(sc[j] - mn);
                l += p;
                const float4* vr = &lv[(sub * 16 + j) * 16];
                #pragma unroll
                for (int d4 = 0; d4 < 16; ++d4) {
                    float4 vv = vr[d4];
                    o[d4*4+0] += p * vv.x;
                    o[d4*4+1] += p * vv.y;
                    o[d4*4+2] += p * vv.z;
                    o[d4*4+3] += p * vv.w;
                }
            }
            m = mn;
        }
    }

    float inv = 1.0f / l;
    float4* op = (float4*)(xout + ((size_t)(b * S_ + s) * DM_ + h * D_));
    #pragma unroll
    for (int d4 = 0; d4 < 16; ++d4) {
        float4 v;
        v.x = o[d4*4+0] * inv; v.y = o[d4*4+1] * inv;
        v.z = o[d4*4+2] * inv; v.w = o[d4*4+3] * inv;
        op[d4] = v;
    }
}

// ---------------------------------------------------------------------------
// Kernel 3: output projection  out[M,1024] = X[M,1024] @ W[1024,1024]
// 64x64 tile / 256 thr / 4x4 per thread, K-step 32. Grid = (16, 256).
// ---------------------------------------------------------------------------
__global__ __launch_bounds__(256) void proj_kernel(
    const float* __restrict__ X,
    const float* __restrict__ Wg,
    float* __restrict__ out)
{
    __shared__ float As[32][68];   // transposed A tile, padded (16B-aligned rows)
    __shared__ float Bs[32][64];
    const int tid = threadIdx.x;
    const int tn  = blockIdx.x;    // 0..15
    const int tm  = blockIdx.y;    // 0..255
    const int tr  = tid >> 4, tc = tid & 15;
    const int m0  = tm * 64, n0 = tn * 64;

    float acc[4][4];
    #pragma unroll
    for (int i = 0; i < 4; ++i)
        #pragma unroll
        for (int j = 0; j < 4; ++j) acc[i][j] = 0.f;

    for (int k0 = 0; k0 < 1024; k0 += 32) {
        __syncthreads();
        // A tile: 64 rows x 32 cols, store transposed
        #pragma unroll
        for (int r = 0; r < 2; ++r) {
            int idx = r * 256 + tid;        // 0..511 float4s
            int row = idx >> 3, c4 = idx & 7;
            float4 a = *(const float4*)(X + (size_t)(m0 + row) * 1024 + k0 + c4 * 4);
            As[c4*4+0][row] = a.x;
            As[c4*4+1][row] = a.y;
            As[c4*4+2][row] = a.z;
            As[c4*4+3][row] = a.w;
        }
        // B tile: 32 rows x 64 cols
        #pragma unroll
        for (int r = 0; r < 2; ++r) {
            int idx = r * 256 + tid;
            int row = idx >> 4, c4 = idx & 15;
            *(float4*)(&Bs[row][c4*4]) =
                *(const float4*)(Wg + (size_t)(k0 + row) * 1024 + n0 + c4 * 4);
        }
        __syncthreads();

        #pragma unroll 8
        for (int k = 0; k < 32; ++k) {
            float4 a4 = *(const float4*)(&As[k][tr * 4]);
            float4 b4 = *(const float4*)(&Bs[k][tc * 4]);
            acc[0][0] += a4.x * b4.x; acc[0][1] += a4.x * b4.y;
            acc[0][2] += a4.x * b4.z; acc[0][3] += a4.x * b4.w;
            acc[1][0] += a4.y * b4.x; acc[1][1] += a4.y * b4.y;
            acc[1][2] += a4.y * b4.z; acc[1][3] += a4.y * b4.w;
            acc[2][0] += a4.z * b4.x; acc[2][1] += a4.z * b4.y;
            acc[2][2] += a4.z * b4.z; acc[2][3] += a4.z * b4.w;
            acc[3][0] += a4.w * b4.x; acc[3][1] += a4.w * b4.y;
            acc[3][2] += a4.w * b4.z; acc[3][3] += a4.w * b4.w;
        }
    }

    #pragma unroll
    for (int i = 0; i < 4; ++i) {
        float4 v = make_float4(acc[i][0], acc[i][1], acc[i][2], acc[i][3]);
        *(float4*)(out + (size_t)(m0 + tr * 4 + i) * 1024 + n0 + tc * 4) = v;
    }
}

// ---------------------------------------------------------------------------
extern "C" void kernel_launch(void* const* d_in, const int* in_sizes, int n_in,
                              void* d_out, int out_size, void* d_ws, size_t ws_size,
                              hipStream_t stream) {
    const float* pre_q = (const float*)d_in[0];
    const float* pre_k = (const float*)d_in[1];
    const float* pre_v = (const float*)d_in[2];
    const float* kkern = (const float*)d_in[3];
    const float* kbias = (const float*)d_in[4];
    const float* vkern = (const float*)d_in[5];
    const float* vbias = (const float*)d_in[6];
    const float* wout  = (const float*)d_in[7];
    float* out = (float*)d_out;

    // workspace layout: X (attn output, 64 MB) | kc (16 MB) | vc (16 MB)
    float* X  = (float*)d_ws;
    float* kc = X + (size_t)B_ * S_ * DM_;
    float* vc = kc + (size_t)B_ * H_ * SC_ * D_;

    compress_kernel<<<B_ * H_ * (SC_ / 32), 256, 0, stream>>>(pre_k, kkern, kbias, kc);
    compress_kernel<<<B_ * H_ * (SC_ / 32), 256, 0, stream>>>(pre_v, vkern, vbias, vc);
    attn_kernel<<<B_ * H_ * (S_ / 256), 256, 0, stream>>>(pre_q, kc, vc, X);
    proj_kernel<<<dim3(DM_ / 64, (B_ * S_) / 64), 256, 0, stream>>>(X, wout, out);
}

// Round 3
// 300.937 us; speedup vs baseline: 4.4242x; 4.4242x over previous
//
#include <hip/hip_runtime.h>
#include <math.h>

#define B_   8
#define S_   2048
#define H_   16
#define D_   64
#define DM_  1024
#define W_   4
#define SC_  512

typedef float f32x4 __attribute__((ext_vector_type(4)));
typedef short bf16x8 __attribute__((ext_vector_type(8)));
typedef short bf16x4 __attribute__((ext_vector_type(4)));

static __device__ inline short f2bf(float f) {
    union { float f; unsigned u; } v; v.f = f;
    unsigned r = v.u + 0x7fffu + ((v.u >> 16) & 1u);   // RNE
    return (short)(r >> 16);
}

// ---------------------------------------------------------------------------
// Kernel 0: W [1024 k][1024 n] f32  ->  Wt [1024 n][1024 k] bf16
// ---------------------------------------------------------------------------
__global__ __launch_bounds__(256) void wtrans_kernel(
    const float* __restrict__ Wg, short* __restrict__ Wt)
{
    __shared__ float ws[64][68];
    const int tid = threadIdx.x;
    const int n0 = blockIdx.x * 64, k0 = blockIdx.y * 64;
    #pragma unroll
    for (int i = 0; i < 4; ++i) {
        int idx = i * 256 + tid;
        int row = idx >> 4, c4 = idx & 15;
        float4 v = *(const float4*)(Wg + (size_t)(k0 + row) * 1024 + n0 + c4 * 4);
        *(float4*)(&ws[row][c4 * 4]) = v;
    }
    __syncthreads();
    #pragma unroll
    for (int i = 0; i < 2; ++i) {
        int idx = i * 256 + tid;
        int n = idx >> 3, kc8 = idx & 7;
        bf16x8 o;
        #pragma unroll
        for (int j = 0; j < 8; ++j) o[j] = f2bf(ws[kc8 * 8 + j][n]);
        *(bf16x8*)(Wt + (size_t)(n0 + n) * 1024 + k0 + kc8 * 8) = o;
    }
}

// ---------------------------------------------------------------------------
// Kernel 1: compression conv.  TR=0: kc[bh][t][dout] bf16 (row-major)
// TR=1: vct[bh][dout][t] bf16, t-columns sigma-permuted within each 32-block
// so attn PV B-fragments are contiguous 16B reads.
// sigma(o) = (o<16) ? (o>>2)*8 + (o&3) : ((o-16)>>2)*8 + 4 + (o&3)
// ---------------------------------------------------------------------------
template<int TR>
__global__ __launch_bounds__(256) void compress_kernel(
    const float* __restrict__ x,     // [B,S,H,D] f32
    const float* __restrict__ kern,  // [W*D, D]
    const float* __restrict__ bias,  // [64]
    short* __restrict__ y)
{
    __shared__ __align__(16) float xs[128 * 64];   // 32 KB
    const int tid   = threadIdx.x;
    const int bid   = blockIdx.x;
    const int chunk = bid & 15;
    const int bh    = bid >> 4;
    const int h     = bh & 15;
    const int b     = bh >> 4;
    const int s0    = chunk * 128;

    float4* xs4 = (float4*)xs;
    #pragma unroll
    for (int r = 0; r < 8; ++r) {
        int idx = r * 256 + tid;
        int row = idx >> 4, c4 = idx & 15;
        const float4* p = (const float4*)(x + (((size_t)(b * S_ + s0 + row) * H_ + h) * D_)) + c4;
        xs4[row * 16 + c4] = *p;
    }
    __syncthreads();

    const int dout = tid & 63;
    const int g    = tid >> 6;
    float bv = bias[dout];
    float acc[8];
    #pragma unroll
    for (int tl = 0; tl < 8; ++tl) acc[tl] = bv;

    const float4* xt4 = xs4 + g * 512;

    #pragma unroll 2
    for (int i4 = 0; i4 < 64; ++i4) {
        float4 xv[8];
        #pragma unroll
        for (int tl = 0; tl < 8; ++tl) xv[tl] = xt4[tl * 64 + i4];
        #pragma unroll
        for (int q = 0; q < 4; ++q) {
            float kw = kern[(i4 * 4 + q) * 64 + dout];
            #pragma unroll
            for (int tl = 0; tl < 8; ++tl)
                acc[tl] += ((const float*)&xv[tl])[q] * kw;
        }
    }

    const int t0 = chunk * 32;
    if (!TR) {
        #pragma unroll
        for (int tl = 0; tl < 8; ++tl) {
            int t = t0 + g * 8 + tl;
            y[((size_t)bh * SC_ + t) * 64 + dout] = f2bf(acc[tl]);
        }
    } else {
        __syncthreads();                       // xs reads done, reuse as staging
        char* sb = (char*)xs;                  // [64 dout][64B] swizzled
        const int swz = (dout & 7) << 4;
        // pos base for the thread's two 4-runs (derived from sigma):
        const int base1 = (g < 2) ? g * 16 : (g - 2) * 16 + 4;
        bf16x4 w0, w1;
        #pragma unroll
        for (int j = 0; j < 4; ++j) { w0[j] = f2bf(acc[j]); w1[j] = f2bf(acc[4 + j]); }
        *(bf16x4*)(sb + ((dout * 64 + base1 * 2) ^ swz)) = w0;
        *(bf16x4*)(sb + ((dout * 64 + base1 * 2 + 16) ^ swz)) = w1;
        __syncthreads();
        int r = tid >> 2, part = tid & 3;
        bf16x8 val = *(bf16x8*)(sb + ((r * 64 + part * 16) ^ ((r & 7) << 4)));
        *(bf16x8*)(y + ((size_t)bh * 64 + r) * SC_ + t0 + part * 8) = val;
    }
}

// ---------------------------------------------------------------------------
// Kernel 2: MFMA flash attention.
// Block = 4 waves, 64 q-rows of one (b,h). Swapped QK^T: D[16k x 16q].
// Lane (hi=l>>4, c=l&15) holds scores k = ks*16+hi*4+r of q-row c.
// P packed in-register; V-fragments read 16B-contiguous from sigma-permuted,
// XOR-swizzled LDS. PV accumulator rows are q = hi*4+r -> rescale factors
// must be broadcast per-row via shfl (round-2 bug fix).
// ---------------------------------------------------------------------------
__global__ __launch_bounds__(256) void attn_kernel(
    const float* __restrict__ q,    // [B,S,H,D] f32
    const short* __restrict__ kc,   // [bh][512][64] bf16
    const short* __restrict__ vct,  // [bh][64][512] bf16 (sigma-permuted cols)
    short* __restrict__ xb)         // [B,S,DM] bf16
{
    __shared__ __align__(16) char vlds[8192];
    const int tid  = threadIdx.x;
    const int bid  = blockIdx.x;
    const int qc   = bid & 31;
    const int bh   = bid >> 5;
    const int h    = bh & 15;
    const int b    = bh >> 4;
    const int w    = tid >> 6;
    const int ln   = tid & 63;
    const int ln15 = ln & 15;
    const int hi   = ln >> 4;
    const int sbase = qc * 64;

    // Q B-fragments (1/sqrt(64) folded into q before rounding — exact pow2)
    bf16x8 qb[2];
    {
        const float* qrow = q + (((size_t)(b * S_ + sbase + w * 16 + ln15)) * H_ + h) * D_;
        #pragma unroll
        for (int dblk = 0; dblk < 2; ++dblk) {
            const float* p = qrow + dblk * 32 + hi * 8;
            #pragma unroll
            for (int j = 0; j < 8; ++j) qb[dblk][j] = f2bf(p[j] * 0.125f);
        }
    }
    const short* kbase = kc + (size_t)bh * SC_ * 64;
    const short* vbase = vct + (size_t)bh * 64 * SC_;

    f32x4 oacc[4];
    #pragma unroll
    for (int ns = 0; ns < 4; ++ns) oacc[ns] = (f32x4){0.f, 0.f, 0.f, 0.f};
    float mrun = -1e30f, lrun = 0.f;

    // stage regs for V tile 0
    const int srow = tid >> 3, spart = tid & 7;
    bf16x8 vs0 = *(const bf16x8*)(vbase + (size_t)srow * SC_ + spart * 8);
    bf16x8 vs1 = *(const bf16x8*)(vbase + (size_t)(srow + 32) * SC_ + spart * 8);

    for (int kt = 0; kt < 8; ++kt) {
        // K fragments (global, L1/L2-hot) + QK^T
        bf16x8 ka[4][2];
        const short* ktb = kbase + kt * 64 * 64;
        #pragma unroll
        for (int ks = 0; ks < 4; ++ks)
            #pragma unroll
            for (int dblk = 0; dblk < 2; ++dblk)
                ka[ks][dblk] = *(const bf16x8*)(ktb + (ks * 16 + ln15) * 64 + dblk * 32 + hi * 8);

        f32x4 dsc[4];
        #pragma unroll
        for (int ks = 0; ks < 4; ++ks) {
            dsc[ks] = __builtin_amdgcn_mfma_f32_16x16x32_bf16(ka[ks][0], qb[0], (f32x4){0.f,0.f,0.f,0.f}, 0, 0, 0);
            dsc[ks] = __builtin_amdgcn_mfma_f32_16x16x32_bf16(ka[ks][1], qb[1], dsc[ks], 0, 0, 0);
        }

        __syncthreads();   // all waves done reading vlds (previous tile)
        *(bf16x8*)(vlds + ((srow * 128 + spart * 16) ^ ((srow & 7) << 4))) = vs0;
        *(bf16x8*)(vlds + (((srow + 32) * 128 + spart * 16) ^ (((srow + 32) & 7) << 4))) = vs1;
        if (kt < 7) {   // issue next tile's loads early (hide under softmax+PV)
            vs0 = *(const bf16x8*)(vbase + (size_t)srow * SC_ + (kt + 1) * 64 + spart * 8);
            vs1 = *(const bf16x8*)(vbase + (size_t)(srow + 32) * SC_ + (kt + 1) * 64 + spart * 8);
        }

        // online softmax (scores for q-row ln15; 16 of 64 per lane)
        float tm = -1e30f;
        #pragma unroll
        for (int ks = 0; ks < 4; ++ks)
            #pragma unroll
            for (int r = 0; r < 4; ++r) tm = fmaxf(tm, dsc[ks][r]);
        tm = fmaxf(tm, __shfl_xor(tm, 16));
        tm = fmaxf(tm, __shfl_xor(tm, 32));
        float mn = fmaxf(mrun, tm);
        float f = __expf(mrun - mn);
        mrun = mn;
        float p[16];
        float lp = 0.f;
        #pragma unroll
        for (int ks = 0; ks < 4; ++ks)
            #pragma unroll
            for (int r = 0; r < 4; ++r) {
                float e = __expf(dsc[ks][r] - mn);
                p[ks * 4 + r] = e;
                lp += e;
            }
        lp += __shfl_xor(lp, 16);
        lp += __shfl_xor(lp, 32);
        lrun = lrun * f + lp;

        // FIX (round-2 bug): oacc row r is q-row hi*4+r, not ln15 — broadcast
        // each row's rescale factor from the lane that owns that q-row.
        float fr[4];
        #pragma unroll
        for (int r = 0; r < 4; ++r) fr[r] = __shfl(f, hi * 4 + r);
        #pragma unroll
        for (int ns = 0; ns < 4; ++ns)
            #pragma unroll
            for (int r = 0; r < 4; ++r) oacc[ns][r] *= fr[r];

        bf16x8 pa[2];
        #pragma unroll
        for (int j = 0; j < 8; ++j) { pa[0][j] = f2bf(p[j]); pa[1][j] = f2bf(p[8 + j]); }

        __syncthreads();   // V tile kt visible
        #pragma unroll
        for (int kb = 0; kb < 2; ++kb)
            #pragma unroll
            for (int ns = 0; ns < 4; ++ns) {
                int row = ns * 16 + ln15;
                bf16x8 vb = *(const bf16x8*)(vlds + ((row * 128 + kb * 64 + hi * 16) ^ ((row & 7) << 4)));
                oacc[ns] = __builtin_amdgcn_mfma_f32_16x16x32_bf16(pa[kb], vb, oacc[ns], 0, 0, 0);
            }
    }

    // epilogue: lane holds O rows q = hi*4+r, col d = ns*16+ln15
    float li[4];
    #pragma unroll
    for (int r = 0; r < 4; ++r) li[r] = 1.f / __shfl(lrun, hi * 4 + r);
    #pragma unroll
    for (int ns = 0; ns < 4; ++ns)
        #pragma unroll
        for (int r = 0; r < 4; ++r) {
            size_t idx = ((size_t)(b * S_ + sbase + w * 16 + hi * 4 + r)) * DM_ + h * 64 + ns * 16 + ln15;
            xb[idx] = f2bf(oacc[ns][r] * li[r]);
        }
}

// ---------------------------------------------------------------------------
// Kernel 3: out[16384,1024] = Xb @ Wt^T  (both bf16, f32 accum/output)
// 128x128 tile, BK=32, 4 waves (2x2 of 64x64), swizzled LDS, reg prefetch.
// ---------------------------------------------------------------------------
__global__ __launch_bounds__(256) void proj_kernel(
    const short* __restrict__ Xb,   // [16384][1024] bf16
    const short* __restrict__ Wt,   // [1024 n][1024 k] bf16
    float* __restrict__ out)        // [16384][1024] f32
{
    __shared__ __align__(16) char As[8192];
    __shared__ __align__(16) char Bs[8192];
    const int tid  = threadIdx.x;
    const int wid  = tid >> 6;
    const int ln   = tid & 63;
    const int ln15 = ln & 15;
    const int hi   = ln >> 4;
    const int wr   = wid >> 1, wc = wid & 1;
    const int m0   = blockIdx.y * 128, n0 = blockIdx.x * 128;
    const int srow = tid >> 2, spart = tid & 3;

    f32x4 acc[4][4];
    #pragma unroll
    for (int i = 0; i < 4; ++i)
        #pragma unroll
        for (int j = 0; j < 4; ++j) acc[i][j] = (f32x4){0.f, 0.f, 0.f, 0.f};

    bf16x8 a0 = *(const bf16x8*)(Xb + (size_t)(m0 + srow) * 1024 + spart * 8);
    bf16x8 a1 = *(const bf16x8*)(Xb + (size_t)(m0 + srow + 64) * 1024 + spart * 8);
    bf16x8 b0 = *(const bf16x8*)(Wt + (size_t)(n0 + srow) * 1024 + spart * 8);
    bf16x8 b1 = *(const bf16x8*)(Wt + (size_t)(n0 + srow + 64) * 1024 + spart * 8);

    for (int k0 = 0; k0 < 1024; k0 += 32) {
        __syncthreads();
        *(bf16x8*)(As + ((srow * 64 + spart * 16) ^ ((srow & 7) << 4))) = a0;
        *(bf16x8*)(As + (((srow + 64) * 64 + spart * 16) ^ (((srow + 64) & 7) << 4))) = a1;
        *(bf16x8*)(Bs + ((srow * 64 + spart * 16) ^ ((srow & 7) << 4))) = b0;
        *(bf16x8*)(Bs + (((srow + 64) * 64 + spart * 16) ^ (((srow + 64) & 7) << 4))) = b1;
        __syncthreads();
        if (k0 < 992) {
            a0 = *(const bf16x8*)(Xb + (size_t)(m0 + srow) * 1024 + k0 + 32 + spart * 8);
            a1 = *(const bf16x8*)(Xb + (size_t)(m0 + srow + 64) * 1024 + k0 + 32 + spart * 8);
            b0 = *(const bf16x8*)(Wt + (size_t)(n0 + srow) * 1024 + k0 + 32 + spart * 8);
            b1 = *(const bf16x8*)(Wt + (size_t)(n0 + srow + 64) * 1024 + k0 + 32 + spart * 8);
        }
        bf16x8 af[4], bfr[4];
        #pragma unroll
        for (int mf = 0; mf < 4; ++mf) {
            int row = wr * 64 + mf * 16 + ln15;
            af[mf] = *(const bf16x8*)(As + ((row * 64 + hi * 16) ^ ((row & 7) << 4)));
        }
        #pragma unroll
        for (int nf = 0; nf < 4; ++nf) {
            int row = wc * 64 + nf * 16 + ln15;
            bfr[nf] = *(const bf16x8*)(Bs + ((row * 64 + hi * 16) ^ ((row & 7) << 4)));
        }
        #pragma unroll
        for (int mf = 0; mf < 4; ++mf)
            #pragma unroll
            for (int nf = 0; nf < 4; ++nf)
                acc[mf][nf] = __builtin_amdgcn_mfma_f32_16x16x32_bf16(af[mf], bfr[nf], acc[mf][nf], 0, 0, 0);
    }

    #pragma unroll
    for (int mf = 0; mf < 4; ++mf)
        #pragma unroll
        for (int nf = 0; nf < 4; ++nf)
            #pragma unroll
            for (int r = 0; r < 4; ++r)
                out[(size_t)(m0 + wr * 64 + mf * 16 + hi * 4 + r) * 1024 + n0 + wc * 64 + nf * 16 + ln15] =
                    acc[mf][nf][r];
}

// ---------------------------------------------------------------------------
extern "C" void kernel_launch(void* const* d_in, const int* in_sizes, int n_in,
                              void* d_out, int out_size, void* d_ws, size_t ws_size,
                              hipStream_t stream) {
    const float* pre_q = (const float*)d_in[0];
    const float* pre_k = (const float*)d_in[1];
    const float* pre_v = (const float*)d_in[2];
    const float* kkern = (const float*)d_in[3];
    const float* kbias = (const float*)d_in[4];
    const float* vkern = (const float*)d_in[5];
    const float* vbias = (const float*)d_in[6];
    const float* wout  = (const float*)d_in[7];
    float* out = (float*)d_out;

    // ws: Xb 32MB | kc 8MB | vct 8MB | Wt 2MB  (bf16)
    short* Xb  = (short*)d_ws;
    short* kcb = Xb + (size_t)(B_ * S_) * DM_;
    short* vct = kcb + (size_t)B_ * H_ * SC_ * D_;
    short* Wtb = vct + (size_t)B_ * H_ * SC_ * D_;

    wtrans_kernel<<<dim3(16, 16), 256, 0, stream>>>(wout, Wtb);
    compress_kernel<0><<<B_ * H_ * 16, 256, 0, stream>>>(pre_k, kkern, kbias, kcb);
    compress_kernel<1><<<B_ * H_ * 16, 256, 0, stream>>>(pre_v, vkern, vbias, vct);
    attn_kernel<<<B_ * H_ * (S_ / 64), 256, 0, stream>>>(pre_q, kcb, vct, Xb);
    proj_kernel<<<dim3(DM_ / 128, (B_ * S_) / 128), 256, 0, stream>>>(Xb, Wtb, out);
}